// Round 9
// baseline (1494.044 us; speedup 1.0000x reference)
//
#include <hip/hip_runtime.h>
#include <math.h>

typedef int i32x4 __attribute__((ext_vector_type(4)));
typedef float f32x4 __attribute__((ext_vector_type(4)));
typedef float f32x2 __attribute__((ext_vector_type(2)));

#define QMAXF 127.0f
#define EPSQ 1e-8f

__device__ __forceinline__ void gl_lds16(const void* g, void* l) {
  __builtin_amdgcn_global_load_lds(
      (const __attribute__((address_space(1))) unsigned int*)g,
      (__attribute__((address_space(3))) unsigned int*)l, 16, 0, 0);
}
__device__ __forceinline__ void gl_lds4(const void* g, void* l) {
  __builtin_amdgcn_global_load_lds(
      (const __attribute__((address_space(1))) unsigned int*)g,
      (__attribute__((address_space(3))) unsigned int*)l, 4, 0, 0);
}

// Group-of-128 symmetric int8 quant: fp32 in -> int8 q + transposed scales.
// Exact reference math in fp32 (max/127, maximum(.,eps), divide, rint, clip).
__global__ __launch_bounds__(256)
void qdq8(const float* __restrict__ in, char* __restrict__ q,
          float* __restrict__ sT, long n_groups, int gpr, int R) {
  long wid = (long)blockIdx.x * 4 + (threadIdx.x >> 6);
  if (wid >= n_groups) return;
  int lane = threadIdx.x & 63;
  long base = wid * 128 + lane * 2;
  f32x2 v = *(const f32x2*)(in + base);
  float m = fmaxf(fabsf(v.x), fabsf(v.y));
#pragma unroll
  for (int off = 32; off; off >>= 1) m = fmaxf(m, __shfl_xor(m, off));
  float s = fmaxf(m / QMAXF, EPSQ);
  int q0 = (int)fminf(fmaxf(rintf(v.x / s), -QMAXF), QMAXF);
  int q1 = (int)fminf(fmaxf(rintf(v.y / s), -QMAXF), QMAXF);
  *(unsigned short*)(q + base) =
      (unsigned short)((q0 & 0xff) | ((q1 & 0xff) << 8));
  if (lane == 0) {
    long row = wid / gpr;
    long gc = wid - row * gpr;
    sT[gc * (long)R + row] = s;
  }
}

// ---------------------------------------------------------------------------
// int8 GEMM, 64x128 tile, BK=128 (= one quant group), 512 thr / 8 waves
// (2 wm x 4 wn; per-wave 32x32 output per dtype). Per-wave state fits in
// <=128 unified regs (acc 64/32 f32) -> no AGPR shuttle on the rescale, and
// 4 waves/SIMD (2 blocks/CU) give the MFMA->cvt->fma chains enough
// independent streams to overlap. r5 skeleton: stage -> sync -> compute ->
// sync, single-buffered LDS. G4 XOR swizzle both sides (verified r5).
// Exact int32 MFMA per group, fp32 rescale with transposed scales.
// ---------------------------------------------------------------------------

// Fused gate/up GEMM + SwiGLU + hidden group-quant (group = tile's 128 cols).
__global__ __launch_bounds__(512, 4)
void gemm_gu_i8(const char* __restrict__ Aq, const char* __restrict__ Bg,
                const char* __restrict__ Bu,
                const float* __restrict__ sAT, const float* __restrict__ sGT,
                const float* __restrict__ sUT,
                char* __restrict__ Hq, float* __restrict__ sHT,
                int M, int N, int K, int NBN) {
  __shared__ __align__(16) char sA[8192];    // 64 rows x 128 B
  __shared__ __align__(16) char sBG[16384];  // 128 rows x 128 B
  __shared__ __align__(16) char sBU[16384];
  __shared__ float sSa[64], sSg[128], sSu[128];
  __shared__ float rmx[4][64];
  __shared__ float rs[64];

  const int tid = threadIdx.x;
  const int lane = tid & 63;
  const int wid = tid >> 6;
  const int wm = wid >> 2, wn = wid & 3;
  const int wr = wm * 32, wc = wn * 32;
  const int l15 = lane & 15, l16 = lane >> 4;

  const int nwg = gridDim.x;
  const int wg = ((int)blockIdx.x & 7) * (nwg >> 3) + ((int)blockIdx.x >> 3);
  const long m0 = (long)(wg / NBN) * 64;
  const long n0 = (long)(wg % NBN) * 128;

  // staging: A = 512 chunks (1/thread), B = 1024 chunks (2/thread, +64 rows).
  // row&7 invariant under +64 -> same swizzled byte-offset for both chunks.
  const long rowS = tid >> 3;
  const int offS = ((tid & 7) * 16) ^ ((int)(rowS & 7) << 4);
  const long kstr = 64L * K;
  const char* gA0 = Aq + (m0 + rowS) * K + offS;
  const char* gG0 = Bg + (n0 + rowS) * K + offS;
  const char* gU0 = Bu + (n0 + rowS) * K + offS;

  const int rdSwz = (l15 & 7) << 4;
  const int colK0 = (l16 * 16) ^ rdSwz;
  const int colK1 = (64 + l16 * 16) ^ rdSwz;

  f32x4 accg[2][2], accu[2][2];
#pragma unroll
  for (int i = 0; i < 2; i++)
#pragma unroll
    for (int j = 0; j < 2; j++) {
      accg[i][j] = (f32x4){0.f, 0.f, 0.f, 0.f};
      accu[i][j] = (f32x4){0.f, 0.f, 0.f, 0.f};
    }
  const i32x4 iz = {0, 0, 0, 0};
  const int KG = K >> 7;

  for (int g = 0; g < KG; ++g) {
    const long kb = (long)g << 7;
    gl_lds16(gA0 + kb, &sA[tid * 16]);
#pragma unroll
    for (int k = 0; k < 2; k++) {
      gl_lds16(gG0 + kb + k * kstr, &sBG[(tid + 512 * k) * 16]);
      gl_lds16(gU0 + kb + k * kstr, &sBU[(tid + 512 * k) * 16]);
    }
    // scales: wave-uniform LDS base + lane*4 (m104); per-lane global source.
    if (wid == 0) gl_lds4(sAT + (long)g * M + m0 + lane, &sSa[0]);
    else if (wid == 1) gl_lds4(sGT + (long)g * N + n0 + lane, &sSg[0]);
    else if (wid == 2) gl_lds4(sGT + (long)g * N + n0 + 64 + lane, &sSg[64]);
    else if (wid == 3) gl_lds4(sUT + (long)g * N + n0 + lane, &sSu[0]);
    else if (wid == 4) gl_lds4(sUT + (long)g * N + n0 + 64 + lane, &sSu[64]);
    __syncthreads();

    i32x4 af[2][2];
#pragma unroll
    for (int i = 0; i < 2; i++) {
      const int rb = (wr + i * 16 + l15) * 128;
      af[i][0] = *(const i32x4*)&sA[rb + colK0];
      af[i][1] = *(const i32x4*)&sA[rb + colK1];
    }
    f32x4 sa4[2];
#pragma unroll
    for (int i = 0; i < 2; i++)
      sa4[i] = *(const f32x4*)&sSa[wr + i * 16 + l16 * 4];

#pragma unroll
    for (int j = 0; j < 2; j++) {
      const int rbB = (wc + j * 16 + l15) * 128;
      i32x4 bgf[2], buf_[2];
      bgf[0] = *(const i32x4*)&sBG[rbB + colK0];
      bgf[1] = *(const i32x4*)&sBG[rbB + colK1];
      buf_[0] = *(const i32x4*)&sBU[rbB + colK0];
      buf_[1] = *(const i32x4*)&sBU[rbB + colK1];
      float sbg = sSg[wc + j * 16 + l15];
      float sbu = sSu[wc + j * 16 + l15];
#pragma unroll
      for (int i = 0; i < 2; i++) {
        i32x4 tg = __builtin_amdgcn_mfma_i32_16x16x64_i8(af[i][0], bgf[0], iz, 0, 0, 0);
        tg = __builtin_amdgcn_mfma_i32_16x16x64_i8(af[i][1], bgf[1], tg, 0, 0, 0);
        i32x4 tu = __builtin_amdgcn_mfma_i32_16x16x64_i8(af[i][0], buf_[0], iz, 0, 0, 0);
        tu = __builtin_amdgcn_mfma_i32_16x16x64_i8(af[i][1], buf_[1], tu, 0, 0, 0);
        accg[i][j] += (sa4[i] * sbg) * __builtin_convertvector(tg, f32x4);
        accu[i][j] += (sa4[i] * sbu) * __builtin_convertvector(tu, f32x4);
      }
    }
    __syncthreads();
  }

  // ---- epilogue: h = silu(g)*u; per-row (tile = one 128-col group) max -> s.
  float pm[2][4];
#pragma unroll
  for (int i = 0; i < 2; i++)
#pragma unroll
    for (int r = 0; r < 4; r++) pm[i][r] = 0.f;
#pragma unroll
  for (int i = 0; i < 2; i++)
#pragma unroll
    for (int j = 0; j < 2; j++)
#pragma unroll
      for (int r = 0; r < 4; r++) {
        float gv = accg[i][j][r];
        float h = gv / (1.f + expf(-gv)) * accu[i][j][r];
        accu[i][j][r] = h;
        pm[i][r] = fmaxf(pm[i][r], fabsf(h));
      }
#pragma unroll
  for (int i = 0; i < 2; i++)
#pragma unroll
    for (int r = 0; r < 4; r++) {
      pm[i][r] = fmaxf(pm[i][r], __shfl_xor(pm[i][r], 1));
      pm[i][r] = fmaxf(pm[i][r], __shfl_xor(pm[i][r], 2));
      pm[i][r] = fmaxf(pm[i][r], __shfl_xor(pm[i][r], 4));
      pm[i][r] = fmaxf(pm[i][r], __shfl_xor(pm[i][r], 8));
    }
#pragma unroll
  for (int i = 0; i < 2; i++)
#pragma unroll
    for (int r = 0; r < 4; r++)
      if (l15 == i * 4 + r) rmx[wn][wr + i * 16 + l16 * 4 + r] = pm[i][r];
  __syncthreads();
  if (tid < 64) {
    float mx = fmaxf(fmaxf(rmx[0][tid], rmx[1][tid]),
                     fmaxf(rmx[2][tid], rmx[3][tid]));
    float s = fmaxf(mx / QMAXF, EPSQ);
    rs[tid] = s;
    sHT[(n0 >> 7) * (long)M + m0 + tid] = s;
  }
  __syncthreads();
  // quantize into sA (K-loop done), then coalesced copy out
#pragma unroll
  for (int i = 0; i < 2; i++) {
    f32x4 sr = *(const f32x4*)&rs[wr + i * 16 + l16 * 4];
#pragma unroll
    for (int j = 0; j < 2; j++)
#pragma unroll
      for (int r = 0; r < 4; r++) {
        float qv = fminf(fmaxf(rintf(accu[i][j][r] / sr[r]), -QMAXF), QMAXF);
        sA[(wr + i * 16 + l16 * 4 + r) * 128 + wc + j * 16 + l15] = (char)(int)qv;
      }
  }
  __syncthreads();
  {
    long row = tid >> 3;
    int off = (tid & 7) * 16;
    *(i32x4*)(Hq + (m0 + row) * N + n0 + off) = *(const i32x4*)&sA[row * 128 + off];
  }
}

// Down GEMM: fp32 out = dequant(A_i8) . dequant(B_i8)^T with exact int cores.
__global__ __launch_bounds__(512, 4)
void gemm_dn_i8(const char* __restrict__ Aq, const char* __restrict__ Bq,
                const float* __restrict__ sAT, const float* __restrict__ sBT,
                float* __restrict__ C, int M, int N, int K, int NBN) {
  __shared__ __align__(16) char sA[8192];
  __shared__ __align__(16) char sB[16384];
  __shared__ float sSa[64], sSb[128];

  const int tid = threadIdx.x;
  const int lane = tid & 63;
  const int wid = tid >> 6;
  const int wm = wid >> 2, wn = wid & 3;
  const int wr = wm * 32, wc = wn * 32;
  const int l15 = lane & 15, l16 = lane >> 4;

  const int nwg = gridDim.x;
  const int wg = ((int)blockIdx.x & 7) * (nwg >> 3) + ((int)blockIdx.x >> 3);
  const long m0 = (long)(wg / NBN) * 64;
  const long n0 = (long)(wg % NBN) * 128;

  const long rowS = tid >> 3;
  const int offS = ((tid & 7) * 16) ^ ((int)(rowS & 7) << 4);
  const long kstr = 64L * K;
  const char* gA0 = Aq + (m0 + rowS) * K + offS;
  const char* gB0 = Bq + (n0 + rowS) * K + offS;

  const int rdSwz = (l15 & 7) << 4;
  const int colK0 = (l16 * 16) ^ rdSwz;
  const int colK1 = (64 + l16 * 16) ^ rdSwz;

  f32x4 acc[2][2];
#pragma unroll
  for (int i = 0; i < 2; i++)
#pragma unroll
    for (int j = 0; j < 2; j++) acc[i][j] = (f32x4){0.f, 0.f, 0.f, 0.f};
  const i32x4 iz = {0, 0, 0, 0};
  const int KG = K >> 7;

  for (int g = 0; g < KG; ++g) {
    const long kb = (long)g << 7;
    gl_lds16(gA0 + kb, &sA[tid * 16]);
#pragma unroll
    for (int k = 0; k < 2; k++)
      gl_lds16(gB0 + kb + k * kstr, &sB[(tid + 512 * k) * 16]);
    if (wid == 0) gl_lds4(sAT + (long)g * M + m0 + lane, &sSa[0]);
    else if (wid == 1) gl_lds4(sBT + (long)g * N + n0 + lane, &sSb[0]);
    else if (wid == 2) gl_lds4(sBT + (long)g * N + n0 + 64 + lane, &sSb[64]);
    __syncthreads();

    i32x4 af[2][2];
#pragma unroll
    for (int i = 0; i < 2; i++) {
      const int rb = (wr + i * 16 + l15) * 128;
      af[i][0] = *(const i32x4*)&sA[rb + colK0];
      af[i][1] = *(const i32x4*)&sA[rb + colK1];
    }
    f32x4 sa4[2];
#pragma unroll
    for (int i = 0; i < 2; i++)
      sa4[i] = *(const f32x4*)&sSa[wr + i * 16 + l16 * 4];

#pragma unroll
    for (int j = 0; j < 2; j++) {
      const int rbB = (wc + j * 16 + l15) * 128;
      i32x4 bf[2];
      bf[0] = *(const i32x4*)&sB[rbB + colK0];
      bf[1] = *(const i32x4*)&sB[rbB + colK1];
      float sb = sSb[wc + j * 16 + l15];
#pragma unroll
      for (int i = 0; i < 2; i++) {
        i32x4 t = __builtin_amdgcn_mfma_i32_16x16x64_i8(af[i][0], bf[0], iz, 0, 0, 0);
        t = __builtin_amdgcn_mfma_i32_16x16x64_i8(af[i][1], bf[1], t, 0, 0, 0);
        acc[i][j] += (sa4[i] * sb) * __builtin_convertvector(t, f32x4);
      }
    }
    __syncthreads();
  }

#pragma unroll
  for (int i = 0; i < 2; i++)
#pragma unroll
    for (int j = 0; j < 2; j++)
#pragma unroll
      for (int r = 0; r < 4; r++) {
        long row = m0 + wr + i * 16 + l16 * 4 + r;
        long col = n0 + wc + j * 16 + l15;
        C[row * N + col] = acc[i][j][r];
      }
}

extern "C" void kernel_launch(void* const* d_in, const int* in_sizes, int n_in,
                              void* d_out, int out_size, void* d_ws, size_t ws_size,
                              hipStream_t stream) {
  (void)n_in; (void)out_size;
  const float* x  = (const float*)d_in[0];
  const float* wg = (const float*)d_in[1];
  const float* wu = (const float*)d_in[2];
  const float* wd = (const float*)d_in[3];
  float* out = (float*)d_out;

  const long H = 4096;
  const long M = in_sizes[0] / H;   // 4096 (B*S)
  const long I = in_sizes[1] / H;   // 11008
  const long GH = H >> 7;           // 32
  const long GI = I >> 7;           // 86

  char* ws = (char*)d_ws;
  size_t off = 0;
  char* xq  = ws + off; off += (size_t)(M * H);
  char* wgq = ws + off; off += (size_t)(I * H);
  char* wuq = ws + off; off += (size_t)(I * H);
  char* wdq = ws + off; off += (size_t)(H * I);
  char* hq  = ws + off; off += (size_t)(M * I);
  float* s_x = (float*)(ws + off); off += (size_t)(GH * M) * 4;
  float* s_g = (float*)(ws + off); off += (size_t)(GH * I) * 4;
  float* s_u = (float*)(ws + off); off += (size_t)(GH * I) * 4;
  float* s_d = (float*)(ws + off); off += (size_t)(GI * H) * 4;
  float* s_h = (float*)(ws + off); off += (size_t)(GI * M) * 4;
  if (ws_size < off) return;

  // 1) int8 group-quant of inputs/weights (q + transposed scales)
  {
    long ng;
    ng = M * H / 128;
    qdq8<<<dim3((unsigned)((ng + 3) / 4)), dim3(256), 0, stream>>>(x, xq, s_x, ng, (int)GH, (int)M);
    ng = I * H / 128;
    qdq8<<<dim3((unsigned)((ng + 3) / 4)), dim3(256), 0, stream>>>(wg, wgq, s_g, ng, (int)GH, (int)I);
    qdq8<<<dim3((unsigned)((ng + 3) / 4)), dim3(256), 0, stream>>>(wu, wuq, s_u, ng, (int)GH, (int)I);
    ng = H * I / 128;
    qdq8<<<dim3((unsigned)((ng + 3) / 4)), dim3(256), 0, stream>>>(wd, wdq, s_d, ng, (int)GI, (int)H);
  }

  // 2) fused gate/up int8 GEMM + SwiGLU + hidden quant -> hq, s_h
  {
    const int NBN = (int)GI;                       // 86
    const int grid = (int)(M / 64) * NBN;          // 5504 (%8==0)
    gemm_gu_i8<<<dim3(grid), dim3(512), 0, stream>>>(
        xq, wgq, wuq, s_x, s_g, s_u, hq, s_h, (int)M, (int)I, (int)H, NBN);
  }
  // 3) down int8 GEMM -> fp32 out
  {
    const int NBN = (int)GH;                       // 32
    const int grid = (int)(M / 64) * NBN;          // 2048 (%8==0)
    gemm_dn_i8<<<dim3(grid), dim3(512), 0, stream>>>(
        hq, wdq, s_h, s_d, out, (int)M, (int)H, (int)I, NBN);
  }
}